// Round 10
// baseline (219.614 us; speedup 1.0000x reference)
//
#include <hip/hip_runtime.h>
#include <stdint.h>

// Problem constants (B=4, C=32, H=W=32, HEADS=4, DIM_HEAD=32)
#define HID 4096   // hidden = C*HEADS*DIM_HEAD
#define NSP 1024   // H*W
#define CIN 32
// Requires ws_size >= 151,519,744 bytes (~145 MiB)

typedef unsigned short u16;
typedef float f32x4 __attribute__((ext_vector_type(4)));
typedef _Float16 f16;
typedef _Float16 f16x8 __attribute__((ext_vector_type(8)));
typedef unsigned short u16x4 __attribute__((ext_vector_type(4)));
typedef unsigned short u16x8 __attribute__((ext_vector_type(8)));

__device__ __forceinline__ u16 f2h(float f) {
  return __builtin_bit_cast(u16, (f16)f);
}
__device__ __forceinline__ float h2f(u16 u) {
  return (float)__builtin_bit_cast(f16, u);
}

__device__ __forceinline__ void gload16(const u16* g, u16* l) {
  __builtin_amdgcn_global_load_lds(
      (const __attribute__((address_space(1))) void*)g,
      (__attribute__((address_space(3))) void*)l, 16, 0, 0);
}

// ---------------------------------------------------------------------------
// conv_vk: V and K sections in ONE launch. Grid (64, 4, 8); z<4 -> V (b=z),
// z>=4 -> K with exp (b=z-4). Single unified code path (runtime sec/doexp
// scalars only — NOT the R7 three-path union that spilled). Block = 64 ch x
// 256 n. Output row = (b*4 + (ch&3))*1024 + (ch>>2)   (ch = e*HEADS + hh).
// NOTE (R7/R8): no shuffle/atomic sum epilogues here — they spill to 256
// VGPR. Sums are done by the separate rowinv pass.
// ---------------------------------------------------------------------------
__global__ __launch_bounds__(256) void conv_vk(const float* __restrict__ img,
    const float* __restrict__ wq, const float* __restrict__ bq,
    u16* __restrict__ v, u16* __restrict__ kexp) {
  __shared__ __align__(16) float imgS[32 * 256];
  __shared__ __align__(16) float wS[32 * 64];
  __shared__ float bS[64];
  int t = threadIdx.x;
  int zz = blockIdx.z;
  bool doexp = zz >= 4;
  int b = zz & 3;
  int sec = doexp ? HID : 2 * HID;
  u16* outp = doexp ? kexp : v;
  int ch0 = blockIdx.x * 64, nt0 = blockIdx.y * 256;
  int nl = t & 63, cg = t >> 6;
#pragma unroll
  for (int i = 0; i < 8; i++) {
    int idx = t + i * 256;
    *(f32x4*)&imgS[idx * 4] =
        *(const f32x4*)&img[((size_t)b * CIN + (idx >> 6)) * NSP + nt0 + (idx & 63) * 4];
  }
#pragma unroll
  for (int i = 0; i < 8; i++) {
    int idx = t + i * 256;
    int chl = idx >> 5, c = idx & 31;
    wS[c * 64 + chl] = wq[(size_t)(sec + ch0 + chl) * CIN + c];
  }
  if (t < 64) bS[t] = bq[sec + ch0 + t];
  __syncthreads();
  f32x4 acc[16];
#pragma unroll
  for (int i = 0; i < 16; i++) {
    f32x4 zv = {0.f, 0.f, 0.f, 0.f};
    acc[i] = zv;
  }
#pragma unroll
  for (int c = 0; c < 32; c++) {
    f32x4 x = *(const f32x4*)&imgS[c * 256 + nl * 4];
    const f32x4* wv = (const f32x4*)&wS[c * 64 + cg * 16];
#pragma unroll
    for (int g = 0; g < 4; g++) {
      f32x4 w4 = wv[g];
      acc[g * 4 + 0] += w4[0] * x;
      acc[g * 4 + 1] += w4[1] * x;
      acc[g * 4 + 2] += w4[2] * x;
      acc[g * 4 + 3] += w4[3] * x;
    }
  }
#pragma unroll
  for (int i = 0; i < 16; i++) {
    int ch = ch0 + cg * 16 + i;
    float bias = bS[cg * 16 + i];
    u16x4 o;
#pragma unroll
    for (int j = 0; j < 4; j++) {
      float vv = acc[i][j] + bias;
      if (doexp) vv = __expf(vv);
      o[j] = f2h(vv);
    }
    size_t row = (size_t)(b * 4 + (ch & 3)) * 1024 + (ch >> 2);
    *(u16x4*)&outp[row * NSP + nt0 + nl * 4] = o;
  }
}

// ---------------------------------------------------------------------------
// conv_q: Q section, output TRANSPOSED qt[bh][n][d] = exp(logit) fp16
// UNNORMALIZED. Block = 64 d x 256 n for one bh; grid (16, 4, 16).
// ---------------------------------------------------------------------------
__global__ __launch_bounds__(256) void conv_q(const float* __restrict__ img,
    const float* __restrict__ wq, const float* __restrict__ bq,
    u16* __restrict__ qt) {
  __shared__ __align__(16) float imgS[32 * 256];
  __shared__ __align__(16) float wS[32 * 64];
  __shared__ float bS[64];
  int t = threadIdx.x;
  int d0 = blockIdx.x * 64, nt0 = blockIdx.y * 256, z = blockIdx.z;
  int b = z >> 2, hh = z & 3;
  int dl = t & 15, ng = t >> 4;
#pragma unroll
  for (int i = 0; i < 8; i++) {
    int idx = t + i * 256;
    *(f32x4*)&imgS[idx * 4] =
        *(const f32x4*)&img[((size_t)b * CIN + (idx >> 6)) * NSP + nt0 + (idx & 63) * 4];
  }
#pragma unroll
  for (int i = 0; i < 8; i++) {
    int idx = t + i * 256;
    int chl = idx >> 5, c = idx & 31;
    wS[c * 64 + chl] = wq[(size_t)((d0 + chl) * 4 + hh) * CIN + c];
  }
  if (t < 64) bS[t] = bq[(d0 + t) * 4 + hh];
  __syncthreads();
  f32x4 acc[16];  // acc[j] = 4 d's for n = nt0 + ng + j*16
#pragma unroll
  for (int i = 0; i < 16; i++) {
    f32x4 zv = {0.f, 0.f, 0.f, 0.f};
    acc[i] = zv;
  }
#pragma unroll
  for (int c = 0; c < 32; c++) {
    f32x4 w4 = *(const f32x4*)&wS[c * 64 + dl * 4];
#pragma unroll
    for (int j = 0; j < 16; j++) {
      float x = imgS[c * 256 + ng + j * 16];
      acc[j] += x * w4;
    }
  }
  f32x4 bb = *(const f32x4*)&bS[dl * 4];
  size_t base = (size_t)z * 1024 * 1024;
#pragma unroll
  for (int j = 0; j < 16; j++) {
    int n = nt0 + ng + j * 16;
    u16x4 o;
#pragma unroll
    for (int q = 0; q < 4; q++) o[q] = f2h(__expf(acc[j][q] + bb[q]));
    *(u16x4*)&qt[base + (size_t)n * 1024 + d0 + dl * 4] = o;
  }
}

// ---------------------------------------------------------------------------
// rowinv: per-row inverse sums from the materialized exp buffers (NaN-free
// by construction). Rows 0..16383 -> kinv from kexp; 16384..32767 -> qinv
// (with *scale) from qtexp. One wave per row; grid 8192 x 256.
// ---------------------------------------------------------------------------
__global__ __launch_bounds__(256) void rowinv(const u16* __restrict__ kexp,
    const u16* __restrict__ qtexp, float* __restrict__ kinv,
    float* __restrict__ qinv) {
  int t = threadIdx.x;
  int wv = t >> 6, l = t & 63;
  int row = blockIdx.x * 4 + wv;  // 0..32767
  const u16* src = (row < 16384) ? kexp + (size_t)row * 1024
                                 : qtexp + (size_t)(row - 16384) * 1024;
  const u16x8* p = (const u16x8*)(src + l * 16);
  u16x8 a = p[0], bvec = p[1];
  float s = 0.f;
#pragma unroll
  for (int j = 0; j < 8; j++) s += h2f(a[j]) + h2f(bvec[j]);
#pragma unroll
  for (int off = 32; off > 0; off >>= 1) s += __shfl_xor(s, off);
  if (l == 0) {
    s = fmaxf(s, 1e-20f);
    if (row < 16384) kinv[row] = 1.0f / s;
    else qinv[row - 16384] = 0.17677669529663687f / s;  // scale = 32^-0.5
  }
}

// ---------------------------------------------------------------------------
// gemm8: batched C = (A * B^T) * colscale[col], M=N=K=1024, 16 batches.
// 256x256 tile, BK=64, 8 waves (2M x 4N), 512 thr, LDS 128 KB (2 dbuf).
// Phase-pipelined schedule (T1+T2+T3+T4+T5) — proven at 45.2us/28.7% Mfma.
// C/D map: col=lane&15, row=(lane>>4)*4+reg.
// ---------------------------------------------------------------------------
template <int MB, bool FIRST>
__device__ __forceinline__ void phase_load(int wm, int wn, int l,
    const u16* ASp, const u16* BSp, f16x8 (&bfr)[4][2], f16x8 (&afr)[2][2]) {
  if constexpr (FIRST) {
#pragma unroll
    for (int n = 0; n < 4; n++) {
      int row = wn * 64 + n * 16 + (l & 15);
#pragma unroll
      for (int ks = 0; ks < 2; ks++) {
        int cjs = (ks * 4 + (l >> 4)) ^ (row & 7);
        bfr[n][ks] = *(const f16x8*)&BSp[row * 64 + cjs * 8];
      }
    }
  }
#pragma unroll
  for (int mm = 0; mm < 2; mm++) {
    int row = wm * 128 + (MB + mm) * 16 + (l & 15);
#pragma unroll
    for (int ks = 0; ks < 2; ks++) {
      int cjs = (ks * 4 + (l >> 4)) ^ (row & 7);
      afr[mm][ks] = *(const f16x8*)&ASp[row * 64 + cjs * 8];
    }
  }
}

template <int MB>
__device__ __forceinline__ void phase_fma(f16x8 (&bfr)[4][2], f16x8 (&afr)[2][2],
                                          f32x4 (&acc)[8][4]) {
  __builtin_amdgcn_s_setprio(1);
#pragma unroll
  for (int n = 0; n < 4; n++) {
#pragma unroll
    for (int mm = 0; mm < 2; mm++) {
      acc[MB + mm][n] = __builtin_amdgcn_mfma_f32_16x16x32_f16(
          afr[mm][0], bfr[n][0], acc[MB + mm][n], 0, 0, 0);
      acc[MB + mm][n] = __builtin_amdgcn_mfma_f32_16x16x32_f16(
          afr[mm][1], bfr[n][1], acc[MB + mm][n], 0, 0, 0);
    }
  }
  __builtin_amdgcn_s_setprio(0);
}

#define SCHED0 __builtin_amdgcn_sched_barrier(0)
#define BARRIER() do { SCHED0; __builtin_amdgcn_s_barrier(); SCHED0; } while (0)

__global__ __launch_bounds__(512, 2) void gemm8(const u16* __restrict__ A0,
    const u16* __restrict__ B0, u16* __restrict__ C0,
    const float* __restrict__ colscale) {
  __shared__ __align__(16) u16 AS[2][256 * 64];
  __shared__ __align__(16) u16 BS[2][256 * 64];
  int t = threadIdx.x;
  int w = t >> 6, l = t & 63;
  int wm = w >> 2, wn = w & 3;
  int bid = blockIdx.x;
  int xcd = bid & 7, rr = bid >> 3;        // rr 0..31
  int z = ((rr >> 4) << 3) | xcd;          // each XCD owns z = {xcd, xcd+8}
  int ti = rr & 15, by = ti >> 2, bx = ti & 3;
  const u16* Ag = A0 + (size_t)z * (1024 * 1024) + (size_t)by * 256 * 1024;
  const u16* Bg = B0 + (size_t)z * (1024 * 1024) + (size_t)bx * 256 * 1024;

  f32x4 acc[8][4];
#pragma unroll
  for (int m = 0; m < 8; m++)
#pragma unroll
    for (int n = 0; n < 4; n++) {
      f32x4 zz = {0.f, 0.f, 0.f, 0.f};
      acc[m][n] = zz;
    }
  f16x8 bfr[4][2];

  auto stageH = [&](u16* lds, const u16* g, int half, int k0) {
#pragma unroll
    for (int i = 0; i < 2; i++) {
      int cid = i * 512 + t;
      int r = cid >> 3, cj = cid & 7;
      gload16(g + (size_t)(half * 128 + r) * 1024 + k0 + ((cj ^ (r & 7)) * 8),
              lds + (half * 128 + r) * 64 + cj * 8);
    }
  };

  // prologue: tile0 {B0,B1,A0,A1} + tile1 {B0,B1,A0} = 7 halves, 14 loads
  stageH(BS[0], Bg, 0, 0);
  stageH(BS[0], Bg, 1, 0);
  stageH(AS[0], Ag, 0, 0);
  stageH(AS[0], Ag, 1, 0);
  stageH(BS[1], Bg, 0, 64);
  stageH(BS[1], Bg, 1, 64);
  stageH(AS[1], Ag, 0, 64);
  asm volatile("s_waitcnt vmcnt(6)" ::: "memory");  // tile0 landed
  BARRIER();

  for (int kt = 0; kt < 16; kt++) {
    int pb = kt & 1;
    const u16* ASp = AS[pb];
    const u16* BSp = BS[pb];
    int kN1 = (kt + 1) * 64, kN2 = (kt + 2) * 64;
    f16x8 afr[2][2];
    phase_load<0, true>(wm, wn, l, ASp, BSp, bfr, afr);
    if (kt < 15) stageH(AS[1 - pb], Ag, 1, kN1);
    BARRIER();
    phase_fma<0>(bfr, afr, acc);
    BARRIER();
    phase_load<2, false>(wm, wn, l, ASp, BSp, bfr, afr);
    if (kt < 14) stageH(BS[pb], Bg, 0, kN2);
    BARRIER();
    phase_fma<2>(bfr, afr, acc);
    BARRIER();
    phase_load<4, false>(wm, wn, l, ASp, BSp, bfr, afr);
    if (kt < 14) stageH(BS[pb], Bg, 1, kN2);
    BARRIER();
    phase_fma<4>(bfr, afr, acc);
    BARRIER();
    phase_load<6, false>(wm, wn, l, ASp, BSp, bfr, afr);
    BARRIER();
    phase_fma<6>(bfr, afr, acc);
    BARRIER();
    if (kt < 14) stageH(AS[pb], Ag, 0, kN2);
    if (kt < 15) {
      if (kt == 14) asm volatile("s_waitcnt vmcnt(0)" ::: "memory");
      else          asm volatile("s_waitcnt vmcnt(6)" ::: "memory");
      BARRIER();
    }
  }

  u16* Cp = C0 + (size_t)z * (1024 * 1024);
  const float* csz = colscale + (size_t)z * 1024;
  int rbase = by * 256 + wm * 128 + (l >> 4) * 4;
  int cbase = bx * 256 + wn * 64 + (l & 15);
  float sc[4];
#pragma unroll
  for (int n = 0; n < 4; n++) sc[n] = csz[cbase + n * 16];
#pragma unroll
  for (int m = 0; m < 8; m++)
#pragma unroll
    for (int n = 0; n < 4; n++)
#pragma unroll
      for (int j = 0; j < 4; j++)
        Cp[(size_t)(rbase + m * 16 + j) * 1024 + cbase + n * 16] =
            f2h(acc[m][n][j] * sc[n]);
}

// ---------------------------------------------------------------------------
// oproj: partial[b][kc][o][n] = sum_{c in kc-chunk} att[b][c][n]*w_out[o][c].
// Grid (32 kc, 4 b) — og moved INSIDE as two sequential 16-o passes over the
// same X slice (per-block 256 KB x 16 blocks/XCD = 4 MB = L2; 2nd pass hits
// L2, halving att HBM reads vs the old (32,2,4) grid). Inner loop identical
// to the proven kernel. Partials stored fp16 (values ~0.2 -> ~1e-4 rel err).
// ---------------------------------------------------------------------------
__global__ __launch_bounds__(256) void oproj(const u16* __restrict__ att,
    const float* __restrict__ wout, u16* __restrict__ partial) {
  __shared__ __align__(16) float wS[128 * 20];
  int t = threadIdx.x;
  int kc = blockIdx.x, b = blockIdx.y;
  const u16* X = att + ((size_t)b * HID + kc * 128) * NSP + t * 4;
  for (int og = 0; og < 2; og++) {
    __syncthreads();  // protect wS reuse across og passes
    for (int i = t; i < 128 * 16; i += 256) {
      int cc = i & 127, oo = i >> 7;
      wS[cc * 20 + oo] = wout[(size_t)(og * 16 + oo) * HID + kc * 128 + cc];
    }
    __syncthreads();
    f32x4 acc[16];
#pragma unroll
    for (int o = 0; o < 16; o++) {
      f32x4 zz = {0.f, 0.f, 0.f, 0.f};
      acc[o] = zz;
    }
#pragma unroll 4
    for (int cc = 0; cc < 128; cc++) {
      u16x4 xr = *(const u16x4*)(X + (size_t)cc * NSP);
      f32x4 x = {h2f(xr[0]), h2f(xr[1]), h2f(xr[2]), h2f(xr[3])};
      const f32x4* wv = (const f32x4*)&wS[cc * 20];
#pragma unroll
      for (int g = 0; g < 4; g++) {
        f32x4 w4 = wv[g];
        acc[g * 4 + 0] += w4[0] * x;
        acc[g * 4 + 1] += w4[1] * x;
        acc[g * 4 + 2] += w4[2] * x;
        acc[g * 4 + 3] += w4[3] * x;
      }
    }
#pragma unroll
    for (int o = 0; o < 16; o++) {
      u16x4 st;
#pragma unroll
      for (int j = 0; j < 4; j++) st[j] = f2h(acc[o][j]);
      *(u16x4*)&partial[(((size_t)b * 32 + kc) * 32 + og * 16 + o) * NSP + t * 4] = st;
    }
  }
}

// ---------------------------------------------------------------------------
// reduce_stats: one thread per output element; 32 fp16 kc-partials loaded
// into independent registers (32 loads in flight). Grid 512 x 256.
// ---------------------------------------------------------------------------
__global__ __launch_bounds__(256) void reduce_stats(const u16* __restrict__ partial,
    const float* __restrict__ bout, float* __restrict__ fin,
    float* __restrict__ stats) {
  int t = threadIdx.x;
  int gid = blockIdx.x * 256 + t;  // 131072 = 4b * 32o * 1024n
  int n = gid & 1023;
  int o = (gid >> 10) & 31;
  int b = gid >> 15;
  const u16* p = partial + ((size_t)b * 32 * 32 + o) * NSP + n;
  float v[32];
#pragma unroll
  for (int kc = 0; kc < 32; kc++) v[kc] = h2f(p[(size_t)kc * 32 * NSP]);
  float s = bout[o];
#pragma unroll
  for (int kc = 0; kc < 32; kc++) s += v[kc];
  fin[((size_t)b * 32 + o) * NSP + n] = s;
  float s1 = s, s2 = s * s;
#pragma unroll
  for (int off = 32; off > 0; off >>= 1) {
    s1 += __shfl_xor(s1, off);
    s2 += __shfl_xor(s2, off);
  }
  __shared__ float r1[4], r2[4];
  int wid = t >> 6;
  if ((t & 63) == 0) { r1[wid] = s1; r2[wid] = s2; }
  __syncthreads();
  if (t == 0) {
    stats[blockIdx.x * 2 + 0] = r1[0] + r1[1] + r1[2] + r1[3];
    stats[blockIdx.x * 2 + 1] = r2[0] + r2[1] + r2[2] + r2[3];
  }
}

// ---------------------------------------------------------------------------
// gn_norm: GroupNorm(1, C) per batch; aggregates 128 per-block stats.
// ---------------------------------------------------------------------------
__global__ __launch_bounds__(256) void gn_norm(const float* __restrict__ fin,
    const float* __restrict__ stats, const float* __restrict__ gamma,
    const float* __restrict__ beta, float* __restrict__ out) {
  int t = threadIdx.x;
  int nc = blockIdx.x, b = blockIdx.y;
  float s1 = 0.f, s2 = 0.f;
  for (int i = 0; i < 128; i++) {
    s1 += stats[(b * 128 + i) * 2 + 0];
    s2 += stats[(b * 128 + i) * 2 + 1];
  }
  const float inv_n = 1.0f / 32768.0f;
  float mean = s1 * inv_n;
  float var = s2 * inv_n - mean * mean;
  float rstd = rsqrtf(var + 1e-5f);
  int nl = t & 63, oq = t >> 6;
  int n = nc * 64 + nl;
#pragma unroll
  for (int oo = 0; oo < 8; oo++) {
    int o = oq * 8 + oo;
    float v = fin[((size_t)b * 32 + o) * NSP + n];
    out[((size_t)b * 32 + o) * NSP + n] = (v - mean) * rstd * gamma[o] + beta[o];
  }
}

// ---------------------------------------------------------------------------
extern "C" void kernel_launch(void* const* d_in, const int* in_sizes, int n_in,
                              void* d_out, int out_size, void* d_ws, size_t ws_size,
                              hipStream_t stream) {
  (void)in_sizes; (void)n_in; (void)out_size; (void)ws_size;
  const float* img   = (const float*)d_in[0];
  const float* wqkv  = (const float*)d_in[1];
  const float* bqkv  = (const float*)d_in[2];
  const float* wout  = (const float*)d_in[3];
  const float* bout  = (const float*)d_in[4];
  const float* gamma = (const float*)d_in[5];
  const float* beta  = (const float*)d_in[6];
  char* ws = (char*)d_ws;
  u16*   v       = (u16*)(ws + 0);            // 33,554,432
  u16*   att     = (u16*)(ws + 0);            // alias of v (dead after GEMM1)
  u16*   kexp    = (u16*)(ws + 33554432);     // 33,554,432
  u16*   qtexp   = (u16*)(ws + 67108864);     // 33,554,432
  u16*   ctx     = (u16*)(ws + 100663296);    // 33,554,432
  float* stats   = (float*)(ws + 100663296);  // 4,096 (alias, post-GEMM2)
  u16*   partial = (u16*)(ws + 134217728);    // 8,388,608 fp16 (oproj)
  float* kinv    = (float*)(ws + 134217728);  // 65,536 (pre-oproj)
  float* qinv    = (float*)(ws + 134283264);  // 65,536 (pre-oproj)
  float* fin     = (float*)(ws + 150994944);  // 524,288
  float* out = (float*)d_out;

  conv_vk<<<dim3(64, 4, 8), 256, 0, stream>>>(img, wqkv, bqkv, v, kexp);
  conv_q<<<dim3(16, 4, 16), 256, 0, stream>>>(img, wqkv, bqkv, qtexp);
  rowinv<<<dim3(8192), 256, 0, stream>>>(kexp, qtexp, kinv, qinv);
  // ctx[e][d] = (sum_n V[e,n] * Kexp[d,n]) * kinv[d]
  gemm8<<<dim3(256), 512, 0, stream>>>(v, kexp, ctx, kinv);
  // att[e][n] = (sum_d ctx[e,d] * qtexp[n,d]) * qinv[n]
  gemm8<<<dim3(256), 512, 0, stream>>>(ctx, qtexp, att, qinv);
  oproj<<<dim3(32, 4), 256, 0, stream>>>(att, wout, partial);
  reduce_stats<<<dim3(512), 256, 0, stream>>>(partial, bout, fin, stats);
  gn_norm<<<dim3(16, 4), 256, 0, stream>>>(fin, stats, gamma, beta, out);
}

// Round 11
// 196.126 us; speedup vs baseline: 1.1198x; 1.1198x over previous
//
#include <hip/hip_runtime.h>
#include <stdint.h>

// Problem constants (B=4, C=32, H=W=32, HEADS=4, DIM_HEAD=32)
#define HID 4096   // hidden = C*HEADS*DIM_HEAD
#define NSP 1024   // H*W
#define CIN 32
// Requires ws_size >= 151,519,744 bytes (~145 MiB)

typedef unsigned short u16;
typedef float f32x4 __attribute__((ext_vector_type(4)));
typedef _Float16 f16;
typedef _Float16 f16x8 __attribute__((ext_vector_type(8)));
typedef unsigned short u16x4 __attribute__((ext_vector_type(4)));
typedef unsigned short u16x8 __attribute__((ext_vector_type(8)));

__device__ __forceinline__ u16 f2h(float f) {
  return __builtin_bit_cast(u16, (f16)f);
}
__device__ __forceinline__ float h2f(u16 u) {
  return (float)__builtin_bit_cast(f16, u);
}

__device__ __forceinline__ void gload16(const u16* g, u16* l) {
  __builtin_amdgcn_global_load_lds(
      (const __attribute__((address_space(1))) void*)g,
      (__attribute__((address_space(3))) void*)l, 16, 0, 0);
}

// ---------------------------------------------------------------------------
// conv_vk: V and K sections in ONE launch. Grid (64, 4, 8); z<4 -> V (b=z),
// z>=4 -> K with exp (b=z-4). Single unified code path (runtime sec/doexp
// scalars only). Block = 64 ch x 256 n. Proven in R10 (no spill).
// Output row = (b*4 + (ch&3))*1024 + (ch>>2)   (ch = e*HEADS + hh).
// ---------------------------------------------------------------------------
__global__ __launch_bounds__(256) void conv_vk(const float* __restrict__ img,
    const float* __restrict__ wq, const float* __restrict__ bq,
    u16* __restrict__ v, u16* __restrict__ kexp) {
  __shared__ __align__(16) float imgS[32 * 256];
  __shared__ __align__(16) float wS[32 * 64];
  __shared__ float bS[64];
  int t = threadIdx.x;
  int zz = blockIdx.z;
  bool doexp = zz >= 4;
  int b = zz & 3;
  int sec = doexp ? HID : 2 * HID;
  u16* outp = doexp ? kexp : v;
  int ch0 = blockIdx.x * 64, nt0 = blockIdx.y * 256;
  int nl = t & 63, cg = t >> 6;
#pragma unroll
  for (int i = 0; i < 8; i++) {
    int idx = t + i * 256;
    *(f32x4*)&imgS[idx * 4] =
        *(const f32x4*)&img[((size_t)b * CIN + (idx >> 6)) * NSP + nt0 + (idx & 63) * 4];
  }
#pragma unroll
  for (int i = 0; i < 8; i++) {
    int idx = t + i * 256;
    int chl = idx >> 5, c = idx & 31;
    wS[c * 64 + chl] = wq[(size_t)(sec + ch0 + chl) * CIN + c];
  }
  if (t < 64) bS[t] = bq[sec + ch0 + t];
  __syncthreads();
  f32x4 acc[16];
#pragma unroll
  for (int i = 0; i < 16; i++) {
    f32x4 zv = {0.f, 0.f, 0.f, 0.f};
    acc[i] = zv;
  }
#pragma unroll
  for (int c = 0; c < 32; c++) {
    f32x4 x = *(const f32x4*)&imgS[c * 256 + nl * 4];
    const f32x4* wv = (const f32x4*)&wS[c * 64 + cg * 16];
#pragma unroll
    for (int g = 0; g < 4; g++) {
      f32x4 w4 = wv[g];
      acc[g * 4 + 0] += w4[0] * x;
      acc[g * 4 + 1] += w4[1] * x;
      acc[g * 4 + 2] += w4[2] * x;
      acc[g * 4 + 3] += w4[3] * x;
    }
  }
#pragma unroll
  for (int i = 0; i < 16; i++) {
    int ch = ch0 + cg * 16 + i;
    float bias = bS[cg * 16 + i];
    u16x4 o;
#pragma unroll
    for (int j = 0; j < 4; j++) {
      float vv = acc[i][j] + bias;
      if (doexp) vv = __expf(vv);
      o[j] = f2h(vv);
    }
    size_t row = (size_t)(b * 4 + (ch & 3)) * 1024 + (ch >> 2);
    *(u16x4*)&outp[row * NSP + nt0 + nl * 4] = o;
  }
}

// ---------------------------------------------------------------------------
// conv_q: Q section, output TRANSPOSED qt[bh][n][d] = exp(logit) fp16
// UNNORMALIZED. Block = 64 d x 256 n for one bh; grid (16, 4, 16).
// ---------------------------------------------------------------------------
__global__ __launch_bounds__(256) void conv_q(const float* __restrict__ img,
    const float* __restrict__ wq, const float* __restrict__ bq,
    u16* __restrict__ qt) {
  __shared__ __align__(16) float imgS[32 * 256];
  __shared__ __align__(16) float wS[32 * 64];
  __shared__ float bS[64];
  int t = threadIdx.x;
  int d0 = blockIdx.x * 64, nt0 = blockIdx.y * 256, z = blockIdx.z;
  int b = z >> 2, hh = z & 3;
  int dl = t & 15, ng = t >> 4;
#pragma unroll
  for (int i = 0; i < 8; i++) {
    int idx = t + i * 256;
    *(f32x4*)&imgS[idx * 4] =
        *(const f32x4*)&img[((size_t)b * CIN + (idx >> 6)) * NSP + nt0 + (idx & 63) * 4];
  }
#pragma unroll
  for (int i = 0; i < 8; i++) {
    int idx = t + i * 256;
    int chl = idx >> 5, c = idx & 31;
    wS[c * 64 + chl] = wq[(size_t)((d0 + chl) * 4 + hh) * CIN + c];
  }
  if (t < 64) bS[t] = bq[(d0 + t) * 4 + hh];
  __syncthreads();
  f32x4 acc[16];  // acc[j] = 4 d's for n = nt0 + ng + j*16
#pragma unroll
  for (int i = 0; i < 16; i++) {
    f32x4 zv = {0.f, 0.f, 0.f, 0.f};
    acc[i] = zv;
  }
#pragma unroll
  for (int c = 0; c < 32; c++) {
    f32x4 w4 = *(const f32x4*)&wS[c * 64 + dl * 4];
#pragma unroll
    for (int j = 0; j < 16; j++) {
      float x = imgS[c * 256 + ng + j * 16];
      acc[j] += x * w4;
    }
  }
  f32x4 bb = *(const f32x4*)&bS[dl * 4];
  size_t base = (size_t)z * 1024 * 1024;
#pragma unroll
  for (int j = 0; j < 16; j++) {
    int n = nt0 + ng + j * 16;
    u16x4 o;
#pragma unroll
    for (int q = 0; q < 4; q++) o[q] = f2h(__expf(acc[j][q] + bb[q]));
    *(u16x4*)&qt[base + (size_t)n * 1024 + d0 + dl * 4] = o;
  }
}

// ---------------------------------------------------------------------------
// rowinv: per-row inverse sums from the materialized exp buffers (NaN-free
// by construction). Rows 0..16383 -> kinv from kexp; 16384..32767 -> qinv
// (with *scale) from qtexp. One wave per row; grid 8192 x 256.
// ---------------------------------------------------------------------------
__global__ __launch_bounds__(256) void rowinv(const u16* __restrict__ kexp,
    const u16* __restrict__ qtexp, float* __restrict__ kinv,
    float* __restrict__ qinv) {
  int t = threadIdx.x;
  int wv = t >> 6, l = t & 63;
  int row = blockIdx.x * 4 + wv;  // 0..32767
  const u16* src = (row < 16384) ? kexp + (size_t)row * 1024
                                 : qtexp + (size_t)(row - 16384) * 1024;
  const u16x8* p = (const u16x8*)(src + l * 16);
  u16x8 a = p[0], bvec = p[1];
  float s = 0.f;
#pragma unroll
  for (int j = 0; j < 8; j++) s += h2f(a[j]) + h2f(bvec[j]);
#pragma unroll
  for (int off = 32; off > 0; off >>= 1) s += __shfl_xor(s, off);
  if (l == 0) {
    s = fmaxf(s, 1e-20f);
    if (row < 16384) kinv[row] = 1.0f / s;
    else qinv[row - 16384] = 0.17677669529663687f / s;  // scale = 32^-0.5
  }
}

// ---------------------------------------------------------------------------
// gemm8: batched C = (A * B^T) * colscale[col], M=N=K=1024, 16 batches.
// 256x256 tile, BK=64, 8 waves (2M x 4N), 512 thr, LDS 128 KB (2 dbuf).
// Phase-pipelined schedule (T1+T2+T3+T4+T5) — proven at 45.2us/28.7% Mfma.
// C/D map: col=lane&15, row=(lane>>4)*4+reg.
// ---------------------------------------------------------------------------
template <int MB, bool FIRST>
__device__ __forceinline__ void phase_load(int wm, int wn, int l,
    const u16* ASp, const u16* BSp, f16x8 (&bfr)[4][2], f16x8 (&afr)[2][2]) {
  if constexpr (FIRST) {
#pragma unroll
    for (int n = 0; n < 4; n++) {
      int row = wn * 64 + n * 16 + (l & 15);
#pragma unroll
      for (int ks = 0; ks < 2; ks++) {
        int cjs = (ks * 4 + (l >> 4)) ^ (row & 7);
        bfr[n][ks] = *(const f16x8*)&BSp[row * 64 + cjs * 8];
      }
    }
  }
#pragma unroll
  for (int mm = 0; mm < 2; mm++) {
    int row = wm * 128 + (MB + mm) * 16 + (l & 15);
#pragma unroll
    for (int ks = 0; ks < 2; ks++) {
      int cjs = (ks * 4 + (l >> 4)) ^ (row & 7);
      afr[mm][ks] = *(const f16x8*)&ASp[row * 64 + cjs * 8];
    }
  }
}

template <int MB>
__device__ __forceinline__ void phase_fma(f16x8 (&bfr)[4][2], f16x8 (&afr)[2][2],
                                          f32x4 (&acc)[8][4]) {
  __builtin_amdgcn_s_setprio(1);
#pragma unroll
  for (int n = 0; n < 4; n++) {
#pragma unroll
    for (int mm = 0; mm < 2; mm++) {
      acc[MB + mm][n] = __builtin_amdgcn_mfma_f32_16x16x32_f16(
          afr[mm][0], bfr[n][0], acc[MB + mm][n], 0, 0, 0);
      acc[MB + mm][n] = __builtin_amdgcn_mfma_f32_16x16x32_f16(
          afr[mm][1], bfr[n][1], acc[MB + mm][n], 0, 0, 0);
    }
  }
  __builtin_amdgcn_s_setprio(0);
}

#define SCHED0 __builtin_amdgcn_sched_barrier(0)
#define BARRIER() do { SCHED0; __builtin_amdgcn_s_barrier(); SCHED0; } while (0)

__global__ __launch_bounds__(512, 2) void gemm8(const u16* __restrict__ A0,
    const u16* __restrict__ B0, u16* __restrict__ C0,
    const float* __restrict__ colscale) {
  __shared__ __align__(16) u16 AS[2][256 * 64];
  __shared__ __align__(16) u16 BS[2][256 * 64];
  int t = threadIdx.x;
  int w = t >> 6, l = t & 63;
  int wm = w >> 2, wn = w & 3;
  int bid = blockIdx.x;
  int xcd = bid & 7, rr = bid >> 3;        // rr 0..31
  int z = ((rr >> 4) << 3) | xcd;          // each XCD owns z = {xcd, xcd+8}
  int ti = rr & 15, by = ti >> 2, bx = ti & 3;
  const u16* Ag = A0 + (size_t)z * (1024 * 1024) + (size_t)by * 256 * 1024;
  const u16* Bg = B0 + (size_t)z * (1024 * 1024) + (size_t)bx * 256 * 1024;

  f32x4 acc[8][4];
#pragma unroll
  for (int m = 0; m < 8; m++)
#pragma unroll
    for (int n = 0; n < 4; n++) {
      f32x4 zz = {0.f, 0.f, 0.f, 0.f};
      acc[m][n] = zz;
    }
  f16x8 bfr[4][2];

  auto stageH = [&](u16* lds, const u16* g, int half, int k0) {
#pragma unroll
    for (int i = 0; i < 2; i++) {
      int cid = i * 512 + t;
      int r = cid >> 3, cj = cid & 7;
      gload16(g + (size_t)(half * 128 + r) * 1024 + k0 + ((cj ^ (r & 7)) * 8),
              lds + (half * 128 + r) * 64 + cj * 8);
    }
  };

  // prologue: tile0 {B0,B1,A0,A1} + tile1 {B0,B1,A0} = 7 halves, 14 loads
  stageH(BS[0], Bg, 0, 0);
  stageH(BS[0], Bg, 1, 0);
  stageH(AS[0], Ag, 0, 0);
  stageH(AS[0], Ag, 1, 0);
  stageH(BS[1], Bg, 0, 64);
  stageH(BS[1], Bg, 1, 64);
  stageH(AS[1], Ag, 0, 64);
  asm volatile("s_waitcnt vmcnt(6)" ::: "memory");  // tile0 landed
  BARRIER();

  for (int kt = 0; kt < 16; kt++) {
    int pb = kt & 1;
    const u16* ASp = AS[pb];
    const u16* BSp = BS[pb];
    int kN1 = (kt + 1) * 64, kN2 = (kt + 2) * 64;
    f16x8 afr[2][2];
    phase_load<0, true>(wm, wn, l, ASp, BSp, bfr, afr);
    if (kt < 15) stageH(AS[1 - pb], Ag, 1, kN1);
    BARRIER();
    phase_fma<0>(bfr, afr, acc);
    BARRIER();
    phase_load<2, false>(wm, wn, l, ASp, BSp, bfr, afr);
    if (kt < 14) stageH(BS[pb], Bg, 0, kN2);
    BARRIER();
    phase_fma<2>(bfr, afr, acc);
    BARRIER();
    phase_load<4, false>(wm, wn, l, ASp, BSp, bfr, afr);
    if (kt < 14) stageH(BS[pb], Bg, 1, kN2);
    BARRIER();
    phase_fma<4>(bfr, afr, acc);
    BARRIER();
    phase_load<6, false>(wm, wn, l, ASp, BSp, bfr, afr);
    BARRIER();
    phase_fma<6>(bfr, afr, acc);
    BARRIER();
    if (kt < 14) stageH(AS[pb], Ag, 0, kN2);
    if (kt < 15) {
      if (kt == 14) asm volatile("s_waitcnt vmcnt(0)" ::: "memory");
      else          asm volatile("s_waitcnt vmcnt(6)" ::: "memory");
      BARRIER();
    }
  }

  u16* Cp = C0 + (size_t)z * (1024 * 1024);
  const float* csz = colscale + (size_t)z * 1024;
  int rbase = by * 256 + wm * 128 + (l >> 4) * 4;
  int cbase = bx * 256 + wn * 64 + (l & 15);
  float sc[4];
#pragma unroll
  for (int n = 0; n < 4; n++) sc[n] = csz[cbase + n * 16];
#pragma unroll
  for (int m = 0; m < 8; m++)
#pragma unroll
    for (int n = 0; n < 4; n++)
#pragma unroll
      for (int j = 0; j < 4; j++)
        Cp[(size_t)(rbase + m * 16 + j) * 1024 + cbase + n * 16] =
            f2h(acc[m][n][j] * sc[n]);
}

// ---------------------------------------------------------------------------
// oproj: partial[b][kc][o][n] = sum_{c in kc-chunk} att[b][c][n]*w_out[o][c].
// Grid (32 kc, 2 og, 4 b) = 256 blocks — the PROVEN R5-R9 structure (R10's
// 128-block og-inside variant starved the GPU: occupancy 4.9%, 59 us).
// Only change vs R9: partials stored fp16 (accuracy proven in R10).
// ---------------------------------------------------------------------------
__global__ __launch_bounds__(256) void oproj(const u16* __restrict__ att,
    const float* __restrict__ wout, u16* __restrict__ partial) {
  __shared__ __align__(16) float wS[128 * 20];
  int t = threadIdx.x;
  int kc = blockIdx.x, og = blockIdx.y, b = blockIdx.z;
  for (int i = t; i < 128 * 16; i += 256) {
    int cc = i & 127, oo = i >> 7;
    wS[cc * 20 + oo] = wout[(size_t)(og * 16 + oo) * HID + kc * 128 + cc];
  }
  __syncthreads();
  f32x4 acc[16];
#pragma unroll
  for (int o = 0; o < 16; o++) {
    f32x4 zz = {0.f, 0.f, 0.f, 0.f};
    acc[o] = zz;
  }
  const u16* X = att + ((size_t)b * HID + kc * 128) * NSP + t * 4;
#pragma unroll 4
  for (int cc = 0; cc < 128; cc++) {
    u16x4 xr = *(const u16x4*)(X + (size_t)cc * NSP);
    f32x4 x = {h2f(xr[0]), h2f(xr[1]), h2f(xr[2]), h2f(xr[3])};
    const f32x4* wv = (const f32x4*)&wS[cc * 20];
#pragma unroll
    for (int g = 0; g < 4; g++) {
      f32x4 w4 = wv[g];
      acc[g * 4 + 0] += w4[0] * x;
      acc[g * 4 + 1] += w4[1] * x;
      acc[g * 4 + 2] += w4[2] * x;
      acc[g * 4 + 3] += w4[3] * x;
    }
  }
#pragma unroll
  for (int o = 0; o < 16; o++) {
    u16x4 st;
#pragma unroll
    for (int j = 0; j < 4; j++) st[j] = f2h(acc[o][j]);
    *(u16x4*)&partial[(((size_t)b * 32 + kc) * 32 + og * 16 + o) * NSP + t * 4] = st;
  }
}

// ---------------------------------------------------------------------------
// reduce_stats: one thread per output element; 32 fp16 kc-partials loaded
// into independent registers (32 loads in flight). Grid 512 x 256.
// ---------------------------------------------------------------------------
__global__ __launch_bounds__(256) void reduce_stats(const u16* __restrict__ partial,
    const float* __restrict__ bout, float* __restrict__ fin,
    float* __restrict__ stats) {
  int t = threadIdx.x;
  int gid = blockIdx.x * 256 + t;  // 131072 = 4b * 32o * 1024n
  int n = gid & 1023;
  int o = (gid >> 10) & 31;
  int b = gid >> 15;
  const u16* p = partial + ((size_t)b * 32 * 32 + o) * NSP + n;
  float v[32];
#pragma unroll
  for (int kc = 0; kc < 32; kc++) v[kc] = h2f(p[(size_t)kc * 32 * NSP]);
  float s = bout[o];
#pragma unroll
  for (int kc = 0; kc < 32; kc++) s += v[kc];
  fin[((size_t)b * 32 + o) * NSP + n] = s;
  float s1 = s, s2 = s * s;
#pragma unroll
  for (int off = 32; off > 0; off >>= 1) {
    s1 += __shfl_xor(s1, off);
    s2 += __shfl_xor(s2, off);
  }
  __shared__ float r1[4], r2[4];
  int wid = t >> 6;
  if ((t & 63) == 0) { r1[wid] = s1; r2[wid] = s2; }
  __syncthreads();
  if (t == 0) {
    stats[blockIdx.x * 2 + 0] = r1[0] + r1[1] + r1[2] + r1[3];
    stats[blockIdx.x * 2 + 1] = r2[0] + r2[1] + r2[2] + r2[3];
  }
}

// ---------------------------------------------------------------------------
// gn_norm: GroupNorm(1, C) per batch; aggregates 128 per-block stats.
// ---------------------------------------------------------------------------
__global__ __launch_bounds__(256) void gn_norm(const float* __restrict__ fin,
    const float* __restrict__ stats, const float* __restrict__ gamma,
    const float* __restrict__ beta, float* __restrict__ out) {
  int t = threadIdx.x;
  int nc = blockIdx.x, b = blockIdx.y;
  float s1 = 0.f, s2 = 0.f;
  for (int i = 0; i < 128; i++) {
    s1 += stats[(b * 128 + i) * 2 + 0];
    s2 += stats[(b * 128 + i) * 2 + 1];
  }
  const float inv_n = 1.0f / 32768.0f;
  float mean = s1 * inv_n;
  float var = s2 * inv_n - mean * mean;
  float rstd = rsqrtf(var + 1e-5f);
  int nl = t & 63, oq = t >> 6;
  int n = nc * 64 + nl;
#pragma unroll
  for (int oo = 0; oo < 8; oo++) {
    int o = oq * 8 + oo;
    float v = fin[((size_t)b * 32 + o) * NSP + n];
    out[((size_t)b * 32 + o) * NSP + n] = (v - mean) * rstd * gamma[o] + beta[o];
  }
}

// ---------------------------------------------------------------------------
extern "C" void kernel_launch(void* const* d_in, const int* in_sizes, int n_in,
                              void* d_out, int out_size, void* d_ws, size_t ws_size,
                              hipStream_t stream) {
  (void)in_sizes; (void)n_in; (void)out_size; (void)ws_size;
  const float* img   = (const float*)d_in[0];
  const float* wqkv  = (const float*)d_in[1];
  const float* bqkv  = (const float*)d_in[2];
  const float* wout  = (const float*)d_in[3];
  const float* bout  = (const float*)d_in[4];
  const float* gamma = (const float*)d_in[5];
  const float* beta  = (const float*)d_in[6];
  char* ws = (char*)d_ws;
  u16*   v       = (u16*)(ws + 0);            // 33,554,432
  u16*   att     = (u16*)(ws + 0);            // alias of v (dead after GEMM1)
  u16*   kexp    = (u16*)(ws + 33554432);     // 33,554,432
  u16*   qtexp   = (u16*)(ws + 67108864);     // 33,554,432
  u16*   ctx     = (u16*)(ws + 100663296);    // 33,554,432
  float* stats   = (float*)(ws + 100663296);  // 4,096 (alias, post-GEMM2)
  u16*   partial = (u16*)(ws + 134217728);    // 8,388,608 fp16 (oproj)
  float* kinv    = (float*)(ws + 134217728);  // 65,536 (pre-oproj)
  float* qinv    = (float*)(ws + 134283264);  // 65,536 (pre-oproj)
  float* fin     = (float*)(ws + 150994944);  // 524,288
  float* out = (float*)d_out;

  conv_vk<<<dim3(64, 4, 8), 256, 0, stream>>>(img, wqkv, bqkv, v, kexp);
  conv_q<<<dim3(16, 4, 16), 256, 0, stream>>>(img, wqkv, bqkv, qtexp);
  rowinv<<<dim3(8192), 256, 0, stream>>>(kexp, qtexp, kinv, qinv);
  // ctx[e][d] = (sum_n V[e,n] * Kexp[d,n]) * kinv[d]
  gemm8<<<dim3(256), 512, 0, stream>>>(v, kexp, ctx, kinv);
  // att[e][n] = (sum_d ctx[e,d] * qtexp[n,d]) * qinv[n]
  gemm8<<<dim3(256), 512, 0, stream>>>(ctx, qtexp, att, qinv);
  oproj<<<dim3(32, 2, 4), 256, 0, stream>>>(att, wout, partial);
  reduce_stats<<<dim3(512), 256, 0, stream>>>(partial, bout, fin, stats);
  gn_norm<<<dim3(16, 4), 256, 0, stream>>>(fin, stats, gamma, beta, out);
}